// Round 16
// baseline (99.626 us; speedup 1.0000x reference)
//
#include <hip/hip_runtime.h>
#include <hip/hip_bf16.h>

typedef __attribute__((ext_vector_type(8))) short short8_t;
typedef __attribute__((ext_vector_type(4))) unsigned short ushort4_t;
typedef __attribute__((ext_vector_type(4))) float float4_t;

#define B_   4
#define C_   256
#define N_   4096
#define DQK  32
#define LOG2E 1.4426950408889634f

#define VMCNT4   asm volatile("s_waitcnt vmcnt(4)" ::: "memory")
#define VMCNT0   asm volatile("s_waitcnt vmcnt(0)" ::: "memory")
#define LGKM0    asm volatile("s_waitcnt lgkmcnt(0)" ::: "memory")
#define SBAR     __builtin_amdgcn_s_barrier()
#define SCHEDB   __builtin_amdgcn_sched_barrier(0)

__device__ __forceinline__ unsigned short f2bf(float x) {
    union { float f; unsigned int u; } v; v.f = x;
    unsigned int r = v.u + 0x7FFFu + ((v.u >> 16) & 1u);   // RNE
    return (unsigned short)(r >> 16);
}
__device__ __forceinline__ unsigned short f2bf_hw(float x) {
    return __bfloat16_as_ushort(__float2bfloat16(x));      // hw RNE, pairs to cvt_pk
}
__device__ __forceinline__ float bf2f(unsigned short u) {
    union { unsigned int u; float f; } v; v.u = ((unsigned int)u) << 16; return v.f;
}

// ---------------- weight casts ----------------
__global__ __launch_bounds__(256) void cast_w_k(
        const float* __restrict__ Wq, const float* __restrict__ Wk,
        const float* __restrict__ Wv,
        unsigned short* __restrict__ Wqb, unsigned short* __restrict__ Wkb,
        unsigned short* __restrict__ Wvb) {
    int i = blockIdx.x * 256 + threadIdx.x;
    if (i < 8192)            Wqb[i] = f2bf(Wq[i]);
    else if (i < 16384)      Wkb[i - 8192] = f2bf(Wk[i - 8192]);
    else                     Wvb[i - 16384] = f2bf(Wv[i - 16384]);
}

// ---------------- pq / pk projection, reading x f32 [b][c][n] directly ----------------
__global__ __launch_bounds__(256) void proj_qk_k(
        const float* __restrict__ q_in, const float* __restrict__ k_in,
        const unsigned short* __restrict__ Wqb, const unsigned short* __restrict__ Wkb,
        const float* __restrict__ bq, const float* __restrict__ bk,
        unsigned short* __restrict__ pqT, unsigned short* __restrict__ pkT) {
    int b = blockIdx.y, z = blockIdx.z;
    const float* X = z ? k_in : q_in;
    const unsigned short* W = z ? Wkb : Wqb;
    const float* bias = z ? bk : bq;
    unsigned short* P = z ? pkT : pqT;
    float scl = z ? 1.0f : LOG2E;
    int tid = threadIdx.x, wave = tid >> 6, lane = tid & 63, l15 = lane & 15, g = lane >> 4;
    int nb = blockIdx.x * 64 + wave * 16;
    float4_t acc0 = {0.f, 0.f, 0.f, 0.f}, acc1 = {0.f, 0.f, 0.f, 0.f};
    const float* Xcol = X + (size_t)b * C_ * N_ + nb + l15;
#pragma unroll
    for (int kk = 0; kk < 8; ++kk) {
        short8_t a;
#pragma unroll
        for (int j = 0; j < 8; ++j)
            a[j] = (short)f2bf(Xcol[(size_t)(kk * 32 + 8 * g + j) * N_]);
        short8_t b0 = *(const short8_t*)(W + (size_t)l15 * C_ + kk * 32 + 8 * g);
        short8_t b1 = *(const short8_t*)(W + (size_t)(16 + l15) * C_ + kk * 32 + 8 * g);
        acc0 = __builtin_amdgcn_mfma_f32_16x16x32_bf16(a, b0, acc0, 0, 0, 0);
        acc1 = __builtin_amdgcn_mfma_f32_16x16x32_bf16(a, b1, acc1, 0, 0, 0);
    }
#pragma unroll
    for (int r = 0; r < 4; ++r) {
        int n = nb + 4 * g + r;
        P[((size_t)b * N_ + n) * DQK + l15]      = f2bf((acc0[r] + bias[l15]) * scl);
        P[((size_t)b * N_ + n) * DQK + 16 + l15] = f2bf((acc1[r] + bias[16 + l15]) * scl);
    }
}

// ---------------- pv projection: pv[b][c][m'] = Wv x v + bv, keys pi-permuted ----------------
__global__ __launch_bounds__(256) void proj_v_k(
        const float* __restrict__ v_in, const unsigned short* __restrict__ Wvb,
        const float* __restrict__ bv, unsigned short* __restrict__ pv) {
    int b = blockIdx.y;
    int tid = threadIdx.x, wave = tid >> 6, lane = tid & 63, l15 = lane & 15, g = lane >> 4;
    int mb = blockIdx.x * 16;
    int m = mb + l15;
    int k32 = m & 31;
    int pcol = (k32 < 16) ? ((k32 >> 2) * 8 + (k32 & 3))
                          : (((k32 - 16) >> 2) * 8 + 4 + (k32 & 3));
    int mcol = (m & ~31) + pcol;
    float4_t acc[4];
#pragma unroll
    for (int i = 0; i < 4; ++i) acc[i] = (float4_t){0.f, 0.f, 0.f, 0.f};
    const float* Vcol = v_in + (size_t)b * C_ * N_ + mb + l15;
#pragma unroll
    for (int kk = 0; kk < 8; ++kk) {
        short8_t bf;
#pragma unroll
        for (int j = 0; j < 8; ++j)
            bf[j] = (short)f2bf(Vcol[(size_t)(kk * 32 + 8 * g + j) * N_]);
#pragma unroll
        for (int ct = 0; ct < 4; ++ct) {
            short8_t af = *(const short8_t*)(Wvb + (size_t)(wave * 64 + ct * 16 + l15) * C_ + kk * 32 + 8 * g);
            acc[ct] = __builtin_amdgcn_mfma_f32_16x16x32_bf16(af, bf, acc[ct], 0, 0, 0);
        }
    }
#pragma unroll
    for (int ct = 0; ct < 4; ++ct)
#pragma unroll
        for (int r = 0; r < 4; ++r) {
            int c = wave * 64 + ct * 16 + 4 * g + r;
            pv[((size_t)b * C_ + c) * N_ + mcol] = f2bf(acc[ct][r] + bv[c]);
        }
}

// ---------------- flash attention: 8-wave blocks, KS=4 -> 3 blocks/CU ----------------
// Identical structure to r15 (best attn: 53.7us): wave w consumes PV for ch
// [32w,32w+32) x 64q; waves 0-3 produce P for q-slice w. V single-buffer
// wave-private; P 16KB ping-pong; ONE barrier/tile. ONLY change vs r15: KS=4
// (1024 blocks) so LDS-allowed 3 blocks/CU (48KB x 3 = 144KB) actually fills:
// 24 waves/CU = 6 contexts/SIMD (VGPR=64 measured, cap 85 satisfied naturally --
// launch_bounds kept at (512,4) to avoid r11's allocator-squeeze spill).
__global__ __launch_bounds__(512, 4) void attn_split_k(
        const unsigned short* __restrict__ pqT, const unsigned short* __restrict__ pkT,
        const unsigned short* __restrict__ pv,
        unsigned short* __restrict__ accP, float* __restrict__ lP, int KS) {
    __shared__ __align__(16) unsigned short VT[256][64];      // 32KB single buffer
    __shared__ __align__(16) short8_t Pl[2][4][2][4][16];     // 16KB [buf][qt][kh][g][l15]
    // XCD-chunked bijective swizzle (nwg % 8 == 0)
    int nqb = gridDim.x;
    int lin = blockIdx.x + nqb * (blockIdx.y + KS * blockIdx.z);
    int cpx = (nqb * KS * 4) >> 3;
    int sl  = (lin & 7) * cpx + (lin >> 3);
    int qbi = sl % nqb;
    int s   = (sl / nqb) % KS;
    int b   = sl / (nqb * KS);

    int kps = N_ / KS, ks0 = s * kps, nt = kps >> 6;
    int tid = threadIdx.x, wave = tid >> 6, lane = tid & 63, l15 = lane & 15, g = lane >> 4;
    int qb = qbi * 64;
    bool prod = wave < 4;
    int qs = wave & 3;
    int rl = lane >> 3, cl = (lane & 7) ^ rl;                 // staging source permute
    int sw = (l15 & 7) << 4;

    short8_t qf = *(const short8_t*)(pqT + ((size_t)b * N_ + qb + qs * 16 + l15) * DQK + 8 * g);
    float4_t acc[2][4];   // [ct][qt] -- 32 VGPR
#pragma unroll
    for (int i = 0; i < 2; ++i)
#pragma unroll
        for (int j = 0; j < 4; ++j) acc[i][j] = (float4_t){0.f, 0.f, 0.f, 0.f};
    float l_acc = 0.f;
    const float4_t zero4 = {0.f, 0.f, 0.f, 0.f};
    const char* pvb8 = (const char*)(pv + (size_t)b * C_ * N_);
    const char* pkTb = (const char*)pkT + (size_t)b * N_ * DQK * 2;

    // persistent byte offsets
    unsigned soff[4];
#pragma unroll
    for (int i = 0; i < 4; ++i)
        soff[i] = (unsigned)(((wave * 32 + i * 8 + rl) * N_ + ks0 + 8 * cl) * 2);
    unsigned koff = (unsigned)(((ks0 + l15) * DQK + 8 * g) * 2);
    // V read bases: rows wave*32 + ct*16 + l15 (imm ct*2048), XOR-swizzled chunks
    const char* vbA = (const char*)&VT[0][0] + (wave * 32 + l15) * 128 + ((16 * g) ^ sw);
    const char* vbB = (const char*)&VT[0][0] + (wave * 32 + l15) * 128 + ((64 + 16 * g) ^ sw);
    // P bases: byte = buf*8192 + qt*2048 + kh*1024 + g*256 + l15*16
    char* PlB = (char*)&Pl[0][0][0][0][0];
    const char* prd = PlB + g * 256 + l15 * 16;               // + buf + qt*2048 + kh*1024
    char* pwr = PlB + qs * 2048 + g * 256 + l15 * 16;         // + buf + kh*1024

    short8_t kf[4];

#define STAGE()                                                               \
    _Pragma("unroll")                                                         \
    for (int i_ = 0; i_ < 4; ++i_) {                                          \
        __builtin_amdgcn_global_load_lds(                                     \
            (const __attribute__((address_space(1))) unsigned int*)(const void*)(pvb8 + soff[i_]), \
            (__attribute__((address_space(3))) unsigned int*)(void*)((char*)&VT[0][0] + (wave * 32 + i_ * 8) * 128), \
            16, 0, 0);                                                        \
        soff[i_] += 128;                                                      \
    }

#define KFLOAD()                                                              \
    _Pragma("unroll")                                                         \
    for (int it_ = 0; it_ < 4; ++it_)                                         \
        kf[it_] = *(const short8_t*)(pkTb + koff + it_ * 1024);               \
    koff += 4096;

#define VREAD(DST)                                                            \
    _Pragma("unroll")                                                         \
    for (int ct_ = 0; ct_ < 2; ++ct_) {                                       \
        DST[ct_][0] = *(const short8_t*)(vbA + ct_ * 2048);                   \
        DST[ct_][1] = *(const short8_t*)(vbB + ct_ * 2048);                   \
    }

#define PFREAD(DST, CBOFF)                                                    \
    _Pragma("unroll")                                                         \
    for (int qt_ = 0; qt_ < 4; ++qt_)                                         \
        _Pragma("unroll")                                                     \
        for (int kh_ = 0; kh_ < 2; ++kh_)                                     \
            DST[qt_][kh_] = *(const short8_t*)(prd + (CBOFF) + qt_ * 2048 + kh_ * 1024);

// QK -> exp2 -> l_acc -> pack -> 2x ds_write_b128 to Pl[NB]
#define QKWR(NBOFF)                                                           \
    {                                                                          \
        float4_t sv_[4];                                                       \
        _Pragma("unroll")                                                      \
        for (int it_ = 0; it_ < 4; ++it_)                                      \
            sv_[it_] = __builtin_amdgcn_mfma_f32_16x16x32_bf16(kf[it_], qf, zero4, 0, 0, 0); \
        float p_[16];                                                          \
        _Pragma("unroll")                                                      \
        for (int it_ = 0; it_ < 4; ++it_)                                      \
            _Pragma("unroll")                                                  \
            for (int r_ = 0; r_ < 4; ++r_)                                     \
                p_[it_ * 4 + r_] = exp2f(sv_[it_][r_]);                        \
        l_acc += ((p_[0] + p_[1]) + (p_[2] + p_[3])) + ((p_[4] + p_[5]) + (p_[6] + p_[7])) \
               + ((p_[8] + p_[9]) + (p_[10] + p_[11])) + ((p_[12] + p_[13]) + (p_[14] + p_[15])); \
        short8_t pb0_, pb1_;                                                   \
        _Pragma("unroll")                                                      \
        for (int j_ = 0; j_ < 4; ++j_) {                                       \
            pb0_[j_]     = (short)f2bf_hw(p_[j_]);                             \
            pb0_[4 + j_] = (short)f2bf_hw(p_[4 + j_]);                         \
            pb1_[j_]     = (short)f2bf_hw(p_[8 + j_]);                         \
            pb1_[4 + j_] = (short)f2bf_hw(p_[12 + j_]);                        \
        }                                                                      \
        *(short8_t*)(pwr + (NBOFF))        = pb0_;                             \
        *(short8_t*)(pwr + (NBOFF) + 1024) = pb1_;                             \
    }

#define PVM(VF, PF)                                                           \
    _Pragma("unroll")                                                         \
    for (int ct_ = 0; ct_ < 2; ++ct_)                                         \
        _Pragma("unroll")                                                     \
        for (int qt_ = 0; qt_ < 4; ++qt_) {                                   \
            acc[ct_][qt_] = __builtin_amdgcn_mfma_f32_16x16x32_bf16(VF[ct_][0], PF[qt_][0], acc[ct_][qt_], 0, 0, 0); \
            acc[ct_][qt_] = __builtin_amdgcn_mfma_f32_16x16x32_bf16(VF[ct_][1], PF[qt_][1], acc[ct_][qt_], 0, 0, 0); \
        }

// body(T): drain own STAGE(T); read V(T)+P(T); drain; re-stage V(T+1);
// producers: QKWR P(T+1) + prefetch kf; PV(T); barrier.
#define BODY(T, CBOFF, NBOFF)                                                 \
    {                                                                          \
        if (prod) { VMCNT4; } else { VMCNT0; }                                 \
        SCHEDB;                                                                \
        short8_t vf_[2][2], pf_[4][2];                                         \
        VREAD(vf_)                                                             \
        PFREAD(pf_, CBOFF)                                                     \
        LGKM0; SCHEDB;                                                         \
        if ((T) + 1 < nt) {                                                    \
            STAGE()                                                            \
            SCHEDB;                                                            \
            if (prod) { QKWR(NBOFF) KFLOAD() }                                 \
            SCHEDB;                                                            \
        }                                                                      \
        __builtin_amdgcn_s_setprio(1);                                         \
        PVM(vf_, pf_)                                                          \
        __builtin_amdgcn_s_setprio(0);                                         \
        LGKM0; SCHEDB;                                                         \
        SBAR;                                                                  \
    }

    // ---- prologue: stage V(0); producers: kf(0) -> P(0) -> kf(1) ----
    STAGE()
    if (prod) {
        KFLOAD()
        QKWR(0)          // P(0) -> buf0 (compiler waits kf; also drains STAGE)
        KFLOAD()
    }
    LGKM0; SCHEDB;
    SBAR;

    for (int t = 0; t < nt; t += 2) {
        BODY(t,     0, 8192)     // read buf0, write buf1
        BODY(t + 1, 8192, 0)     // read buf1, write buf0
    }

    // ---- epilogue: l (producers) + bf16 partial acc ----
    if (prod) {
        l_acc += __shfl_xor(l_acc, 16);
        l_acc += __shfl_xor(l_acc, 32);
        if (g == 0)
            lP[(size_t)(b * KS + s) * N_ + qb + qs * 16 + l15] = l_acc;
    }
    unsigned short* accOut = accP + ((size_t)(b * KS + s) * C_) * N_;
#pragma unroll
    for (int ct = 0; ct < 2; ++ct)
#pragma unroll
        for (int qt = 0; qt < 4; ++qt)
#pragma unroll
            for (int r = 0; r < 4; ++r) {
                int c = wave * 32 + ct * 16 + 4 * g + r;
                accOut[(size_t)c * N_ + qb + qt * 16 + l15] = f2bf_hw(acc[ct][qt][r]);
            }
#undef STAGE
#undef KFLOAD
#undef VREAD
#undef PFREAD
#undef QKWR
#undef PVM
#undef BODY
}

// ---------------- combine splits (bf16 partials) + normalize + gamma*out + v ----------------
__global__ __launch_bounds__(256) void combine_k(
        const unsigned short* __restrict__ accP, const float* __restrict__ lP,
        const float* __restrict__ v_in, const float* __restrict__ gamma,
        float* __restrict__ out, int KS) {
    int i = blockIdx.x * 256 + threadIdx.x;
    const int nq4 = N_ / 4;
    int q0 = (i % nq4) * 4;
    int c  = (i / nq4) % C_;
    int b  = i / (nq4 * C_);
    float4_t num = {0.f, 0.f, 0.f, 0.f}, den = {0.f, 0.f, 0.f, 0.f};
    for (int s = 0; s < KS; ++s) {
        float4_t l4 = *(const float4_t*)(lP + (size_t)(b * KS + s) * N_ + q0);
        ushort4_t a4 = *(const ushort4_t*)(accP + ((size_t)(b * KS + s) * C_ + c) * N_ + q0);
#pragma unroll
        for (int j = 0; j < 4; ++j) {
            den[j] += l4[j];
            num[j] += bf2f(a4[j]);
        }
    }
    float gm = gamma[0];
    size_t idx = ((size_t)(b * C_ + c)) * N_ + q0;
    float4_t vi = *(const float4_t*)(v_in + idx);
    float4_t o;
#pragma unroll
    for (int j = 0; j < 4; ++j) o[j] = gm * num[j] / den[j] + vi[j];
    *(float4_t*)(out + idx) = o;
}

extern "C" void kernel_launch(void* const* d_in, const int* in_sizes, int n_in,
                              void* d_out, int out_size, void* d_ws, size_t ws_size,
                              hipStream_t stream) {
    (void)in_sizes; (void)n_in; (void)out_size;
    const float* v_in  = (const float*)d_in[0];
    const float* k_in  = (const float*)d_in[1];
    const float* q_in  = (const float*)d_in[2];
    const float* Wq    = (const float*)d_in[3];
    const float* bq    = (const float*)d_in[4];
    const float* Wk    = (const float*)d_in[5];
    const float* bk    = (const float*)d_in[6];
    const float* Wv    = (const float*)d_in[7];
    const float* bv    = (const float*)d_in[8];
    const float* gamma = (const float*)d_in[9];
    float* out = (float*)d_out;

    char* ws = (char*)d_ws;
    unsigned short* pvb = (unsigned short*)(ws + 0);          // 8.39 MB + 16 KB pad
    unsigned short* pqT = (unsigned short*)(ws + 8404992);    // 1 MB [b][n][32] (x log2e)
    unsigned short* pkT = (unsigned short*)(ws + 9453568);    // 1 MB + 24 KB pad (pipelined overread)
    unsigned short* Wqb = (unsigned short*)(ws + 10526720);   // 16 KB
    unsigned short* Wkb = (unsigned short*)(ws + 10543104);   // 16 KB
    unsigned short* Wvb = (unsigned short*)(ws + 10559488);   // 128 KB
    const size_t base2 = 10690560;

    // accP bf16: KS * 8.39 MB; lP f32: KS * 64 KB
    int KS = 4;
    while (KS > 1) {
        size_t need = base2 + (size_t)KS * 8388608 + (size_t)KS * 65536;
        if (need <= ws_size) break;
        KS >>= 1;
    }
    unsigned short* accP = (unsigned short*)(ws + base2);
    float* lP = (float*)(ws + base2 + (size_t)KS * 8388608);

    cast_w_k<<<320, 256, 0, stream>>>(Wq, Wk, Wv, Wqb, Wkb, Wvb);
    proj_qk_k<<<dim3(64, 4, 2), 256, 0, stream>>>(q_in, k_in, Wqb, Wkb, bq, bk, pqT, pkT);
    proj_v_k<<<dim3(256, 4), 256, 0, stream>>>(v_in, Wvb, bv, pvb);
    attn_split_k<<<dim3(64, KS, 4), 512, 0, stream>>>(pqT, pkT, pvb, accP, lP, KS);
    combine_k<<<4096, 256, 0, stream>>>(accP, lP, v_in, gamma, out, KS);
}

// Round 18
// 99.340 us; speedup vs baseline: 1.0029x; 1.0029x over previous
//
#include <hip/hip_runtime.h>
#include <hip/hip_bf16.h>

typedef __attribute__((ext_vector_type(8))) short short8_t;
typedef __attribute__((ext_vector_type(4))) unsigned short ushort4_t;
typedef __attribute__((ext_vector_type(4))) float float4_t;

#define B_   4
#define C_   256
#define N_   4096
#define DQK  32
#define LOG2E 1.4426950408889634f

#define VMCNT8   asm volatile("s_waitcnt vmcnt(8)" ::: "memory")
#define VMCNT4   asm volatile("s_waitcnt vmcnt(4)" ::: "memory")
#define VMCNT0   asm volatile("s_waitcnt vmcnt(0)" ::: "memory")
#define LGKM0    asm volatile("s_waitcnt lgkmcnt(0)" ::: "memory")
#define SBAR     __builtin_amdgcn_s_barrier()
#define SCHEDB   __builtin_amdgcn_sched_barrier(0)

__device__ __forceinline__ unsigned short f2bf(float x) {
    union { float f; unsigned int u; } v; v.f = x;
    unsigned int r = v.u + 0x7FFFu + ((v.u >> 16) & 1u);   // RNE
    return (unsigned short)(r >> 16);
}
__device__ __forceinline__ unsigned short f2bf_hw(float x) {
    return __bfloat16_as_ushort(__float2bfloat16(x));      // hw RNE, pairs to cvt_pk
}
__device__ __forceinline__ float bf2f(unsigned short u) {
    union { unsigned int u; float f; } v; v.u = ((unsigned int)u) << 16; return v.f;
}

// ---------------- weight casts ----------------
__global__ __launch_bounds__(256) void cast_w_k(
        const float* __restrict__ Wq, const float* __restrict__ Wk,
        const float* __restrict__ Wv,
        unsigned short* __restrict__ Wqb, unsigned short* __restrict__ Wkb,
        unsigned short* __restrict__ Wvb) {
    int i = blockIdx.x * 256 + threadIdx.x;
    if (i < 8192)            Wqb[i] = f2bf(Wq[i]);
    else if (i < 16384)      Wkb[i - 8192] = f2bf(Wk[i - 8192]);
    else                     Wvb[i - 16384] = f2bf(Wv[i - 16384]);
}

// ---------------- pq / pk projection, reading x f32 [b][c][n] directly ----------------
__global__ __launch_bounds__(256) void proj_qk_k(
        const float* __restrict__ q_in, const float* __restrict__ k_in,
        const unsigned short* __restrict__ Wqb, const unsigned short* __restrict__ Wkb,
        const float* __restrict__ bq, const float* __restrict__ bk,
        unsigned short* __restrict__ pqT, unsigned short* __restrict__ pkT) {
    int b = blockIdx.y, z = blockIdx.z;
    const float* X = z ? k_in : q_in;
    const unsigned short* W = z ? Wkb : Wqb;
    const float* bias = z ? bk : bq;
    unsigned short* P = z ? pkT : pqT;
    float scl = z ? 1.0f : LOG2E;
    int tid = threadIdx.x, wave = tid >> 6, lane = tid & 63, l15 = lane & 15, g = lane >> 4;
    int nb = blockIdx.x * 64 + wave * 16;
    float4_t acc0 = {0.f, 0.f, 0.f, 0.f}, acc1 = {0.f, 0.f, 0.f, 0.f};
    const float* Xcol = X + (size_t)b * C_ * N_ + nb + l15;
#pragma unroll
    for (int kk = 0; kk < 8; ++kk) {
        short8_t a;
#pragma unroll
        for (int j = 0; j < 8; ++j)
            a[j] = (short)f2bf(Xcol[(size_t)(kk * 32 + 8 * g + j) * N_]);
        short8_t b0 = *(const short8_t*)(W + (size_t)l15 * C_ + kk * 32 + 8 * g);
        short8_t b1 = *(const short8_t*)(W + (size_t)(16 + l15) * C_ + kk * 32 + 8 * g);
        acc0 = __builtin_amdgcn_mfma_f32_16x16x32_bf16(a, b0, acc0, 0, 0, 0);
        acc1 = __builtin_amdgcn_mfma_f32_16x16x32_bf16(a, b1, acc1, 0, 0, 0);
    }
#pragma unroll
    for (int r = 0; r < 4; ++r) {
        int n = nb + 4 * g + r;
        P[((size_t)b * N_ + n) * DQK + l15]      = f2bf((acc0[r] + bias[l15]) * scl);
        P[((size_t)b * N_ + n) * DQK + 16 + l15] = f2bf((acc1[r] + bias[16 + l15]) * scl);
    }
}

// ---------------- pv projection: pv[b][c][m'] = Wv x v + bv, keys pi-permuted ----------------
__global__ __launch_bounds__(256) void proj_v_k(
        const float* __restrict__ v_in, const unsigned short* __restrict__ Wvb,
        const float* __restrict__ bv, unsigned short* __restrict__ pv) {
    int b = blockIdx.y;
    int tid = threadIdx.x, wave = tid >> 6, lane = tid & 63, l15 = lane & 15, g = lane >> 4;
    int mb = blockIdx.x * 16;
    int m = mb + l15;
    int k32 = m & 31;
    int pcol = (k32 < 16) ? ((k32 >> 2) * 8 + (k32 & 3))
                          : (((k32 - 16) >> 2) * 8 + 4 + (k32 & 3));
    int mcol = (m & ~31) + pcol;
    float4_t acc[4];
#pragma unroll
    for (int i = 0; i < 4; ++i) acc[i] = (float4_t){0.f, 0.f, 0.f, 0.f};
    const float* Vcol = v_in + (size_t)b * C_ * N_ + mb + l15;
#pragma unroll
    for (int kk = 0; kk < 8; ++kk) {
        short8_t bf;
#pragma unroll
        for (int j = 0; j < 8; ++j)
            bf[j] = (short)f2bf(Vcol[(size_t)(kk * 32 + 8 * g + j) * N_]);
#pragma unroll
        for (int ct = 0; ct < 4; ++ct) {
            short8_t af = *(const short8_t*)(Wvb + (size_t)(wave * 64 + ct * 16 + l15) * C_ + kk * 32 + 8 * g);
            acc[ct] = __builtin_amdgcn_mfma_f32_16x16x32_bf16(af, bf, acc[ct], 0, 0, 0);
        }
    }
#pragma unroll
    for (int ct = 0; ct < 4; ++ct)
#pragma unroll
        for (int r = 0; r < 4; ++r) {
            int c = wave * 64 + ct * 16 + 4 * g + r;
            pv[((size_t)b * C_ + c) * N_ + mcol] = f2bf(acc[ct][r] + bv[c]);
        }
}

// ---------------- flash attention: 8-wave blocks, V double-buffered, stage-at-top ----------------
// r15 structure (proven 53.7us, VGPR 64): wave w consumes PV for ch [32w,32w+32)
// x 64q; waves 0-3 produce P for q-slice w. ONLY change: VT double-buffered
// (2x32KB; LDS 80KB = still 2 blocks/CU) and STAGE(V(t+1)) issued at the TOP of
// iter t -- a full iteration ahead of its consumer, so the top vmcnt wait is
// free. vmcnt ledger (no spills; VGPR ~64): steady top = prod VMCNT8 / cons
// VMCNT4 after issuing STAGE (drains stage(t), keeps kf(t+1)+stage(t+1));
// last tile = VMCNT4 / VMCNT0 (r15 values). WAR on buf^1: wave-private rows,
// drained by prev iter's mid-LGKM0.
__global__ __launch_bounds__(512, 4) void attn_split_k(
        const unsigned short* __restrict__ pqT, const unsigned short* __restrict__ pkT,
        const unsigned short* __restrict__ pv,
        unsigned short* __restrict__ accP, float* __restrict__ lP, int KS) {
    __shared__ __align__(16) unsigned short VT[2][256][64];   // 64KB double buffer
    __shared__ __align__(16) short8_t Pl[2][4][2][4][16];     // 16KB [buf][qt][kh][g][l15]
    // XCD-chunked bijective swizzle (nwg % 8 == 0)
    int nqb = gridDim.x;
    int lin = blockIdx.x + nqb * (blockIdx.y + KS * blockIdx.z);
    int cpx = (nqb * KS * 4) >> 3;
    int sl  = (lin & 7) * cpx + (lin >> 3);
    int qbi = sl % nqb;
    int s   = (sl / nqb) % KS;
    int b   = sl / (nqb * KS);

    int kps = N_ / KS, ks0 = s * kps, nt = kps >> 6;
    int tid = threadIdx.x, wave = tid >> 6, lane = tid & 63, l15 = lane & 15, g = lane >> 4;
    int qb = qbi * 64;
    bool prod = wave < 4;
    int qs = wave & 3;
    int rl = lane >> 3, cl = (lane & 7) ^ rl;                 // staging source permute
    int sw = (l15 & 7) << 4;

    short8_t qf = *(const short8_t*)(pqT + ((size_t)b * N_ + qb + qs * 16 + l15) * DQK + 8 * g);
    float4_t acc[2][4];   // [ct][qt] -- 32 VGPR
#pragma unroll
    for (int i = 0; i < 2; ++i)
#pragma unroll
        for (int j = 0; j < 4; ++j) acc[i][j] = (float4_t){0.f, 0.f, 0.f, 0.f};
    float l_acc = 0.f;
    const float4_t zero4 = {0.f, 0.f, 0.f, 0.f};
    const char* pvb8 = (const char*)(pv + (size_t)b * C_ * N_);
    const char* pkTb = (const char*)pkT + (size_t)b * N_ * DQK * 2;

    // persistent byte offsets
    unsigned soff[4];
#pragma unroll
    for (int i = 0; i < 4; ++i)
        soff[i] = (unsigned)(((wave * 32 + i * 8 + rl) * N_ + ks0 + 8 * cl) * 2);
    unsigned koff = (unsigned)(((ks0 + l15) * DQK + 8 * g) * 2);
    // V read bases: rows wave*32 + ct*16 + l15 (imm RB*32768 + ct*2048), XOR-swizzled
    const char* vbA = (const char*)&VT[0][0][0] + (wave * 32 + l15) * 128 + ((16 * g) ^ sw);
    const char* vbB = (const char*)&VT[0][0][0] + (wave * 32 + l15) * 128 + ((64 + 16 * g) ^ sw);
    // P bases: byte = buf*8192 + qt*2048 + kh*1024 + g*256 + l15*16
    char* PlB = (char*)&Pl[0][0][0][0][0];
    const char* prd = PlB + g * 256 + l15 * 16;               // + buf + qt*2048 + kh*1024
    char* pwr = PlB + qs * 2048 + g * 256 + l15 * 16;         // + buf + kh*1024

    short8_t kf[4];

#define STAGE(RBUF)                                                           \
    _Pragma("unroll")                                                         \
    for (int i_ = 0; i_ < 4; ++i_) {                                          \
        __builtin_amdgcn_global_load_lds(                                     \
            (const __attribute__((address_space(1))) unsigned int*)(const void*)(pvb8 + soff[i_]), \
            (__attribute__((address_space(3))) unsigned int*)(void*)((char*)&VT[RBUF][0][0] + (wave * 32 + i_ * 8) * 128), \
            16, 0, 0);                                                        \
        soff[i_] += 128;                                                      \
    }

#define KFLOAD()                                                              \
    _Pragma("unroll")                                                         \
    for (int it_ = 0; it_ < 4; ++it_)                                         \
        kf[it_] = *(const short8_t*)(pkTb + koff + it_ * 1024);               \
    koff += 4096;

#define VREAD(DST, RB)                                                        \
    _Pragma("unroll")                                                         \
    for (int ct_ = 0; ct_ < 2; ++ct_) {                                       \
        DST[ct_][0] = *(const short8_t*)(vbA + (RB) * 32768 + ct_ * 2048);    \
        DST[ct_][1] = *(const short8_t*)(vbB + (RB) * 32768 + ct_ * 2048);    \
    }

#define PFREAD(DST, CBOFF)                                                    \
    _Pragma("unroll")                                                         \
    for (int qt_ = 0; qt_ < 4; ++qt_)                                         \
        _Pragma("unroll")                                                     \
        for (int kh_ = 0; kh_ < 2; ++kh_)                                     \
            DST[qt_][kh_] = *(const short8_t*)(prd + (CBOFF) + qt_ * 2048 + kh_ * 1024);

// QK -> exp2 -> l_acc -> pack -> 2x ds_write_b128 to Pl[NB]
#define QKWR(NBOFF)                                                           \
    {                                                                          \
        float4_t sv_[4];                                                       \
        _Pragma("unroll")                                                      \
        for (int it_ = 0; it_ < 4; ++it_)                                      \
            sv_[it_] = __builtin_amdgcn_mfma_f32_16x16x32_bf16(kf[it_], qf, zero4, 0, 0, 0); \
        float p_[16];                                                          \
        _Pragma("unroll")                                                      \
        for (int it_ = 0; it_ < 4; ++it_)                                      \
            _Pragma("unroll")                                                  \
            for (int r_ = 0; r_ < 4; ++r_)                                     \
                p_[it_ * 4 + r_] = exp2f(sv_[it_][r_]);                        \
        l_acc += ((p_[0] + p_[1]) + (p_[2] + p_[3])) + ((p_[4] + p_[5]) + (p_[6] + p_[7])) \
               + ((p_[8] + p_[9]) + (p_[10] + p_[11])) + ((p_[12] + p_[13]) + (p_[14] + p_[15])); \
        short8_t pb0_, pb1_;                                                   \
        _Pragma("unroll")                                                      \
        for (int j_ = 0; j_ < 4; ++j_) {                                       \
            pb0_[j_]     = (short)f2bf_hw(p_[j_]);                             \
            pb0_[4 + j_] = (short)f2bf_hw(p_[4 + j_]);                         \
            pb1_[j_]     = (short)f2bf_hw(p_[8 + j_]);                         \
            pb1_[4 + j_] = (short)f2bf_hw(p_[12 + j_]);                        \
        }                                                                      \
        *(short8_t*)(pwr + (NBOFF))        = pb0_;                             \
        *(short8_t*)(pwr + (NBOFF) + 1024) = pb1_;                             \
    }

#define PVM(VF, PF)                                                           \
    _Pragma("unroll")                                                         \
    for (int ct_ = 0; ct_ < 2; ++ct_)                                         \
        _Pragma("unroll")                                                     \
        for (int qt_ = 0; qt_ < 4; ++qt_) {                                   \
            acc[ct_][qt_] = __builtin_amdgcn_mfma_f32_16x16x32_bf16(VF[ct_][0], PF[qt_][0], acc[ct_][qt_], 0, 0, 0); \
            acc[ct_][qt_] = __builtin_amdgcn_mfma_f32_16x16x32_bf16(VF[ct_][1], PF[qt_][1], acc[ct_][qt_], 0, 0, 0); \
        }

// body(T): issue STAGE(T+1)->buf^1 at TOP; wait stage(T) (issued a full iter
// ago); read V(T)+P(T); drain; producers QKWR P(T+1) + prefetch kf; PV(T);
// drain P writes; barrier.
#define BODY(T, CBOFF, NBOFF, RB)                                             \
    {                                                                          \
        if ((T) + 1 < nt) {                                                    \
            STAGE((RB) ^ 1)                                                    \
            SCHEDB;                                                            \
            if (prod) { VMCNT8; } else { VMCNT4; }                             \
        } else {                                                               \
            if (prod) { VMCNT4; } else { VMCNT0; }                             \
        }                                                                      \
        SCHEDB;                                                                \
        short8_t vf_[2][2], pf_[4][2];                                         \
        VREAD(vf_, RB)                                                         \
        PFREAD(pf_, CBOFF)                                                     \
        LGKM0; SCHEDB;                                                         \
        if ((T) + 1 < nt) {                                                    \
            if (prod) { QKWR(NBOFF) KFLOAD() }                                 \
            SCHEDB;                                                            \
        }                                                                      \
        __builtin_amdgcn_s_setprio(1);                                         \
        PVM(vf_, pf_)                                                          \
        __builtin_amdgcn_s_setprio(0);                                         \
        LGKM0; SCHEDB;                                                         \
        SBAR;                                                                  \
    }

    // ---- prologue: stage V(0)->buf0; producers: kf(0) -> P(0) -> kf(1) ----
    STAGE(0)
    if (prod) {
        KFLOAD()
        QKWR(0)          // P(0) -> buf0 (compiler waits kf(0) -> drains stage(0))
        KFLOAD()
    }
    LGKM0; SCHEDB;
    SBAR;

    for (int t = 0; t < nt; t += 2) {
        BODY(t,     0, 8192, 0)      // read V buf0 / P buf0, stage V buf1, write P buf1
        BODY(t + 1, 8192, 0, 1)      // read V buf1 / P buf1, stage V buf0, write P buf0
    }

    // ---- epilogue: l (producers) + bf16 partial acc ----
    if (prod) {
        l_acc += __shfl_xor(l_acc, 16);
        l_acc += __shfl_xor(l_acc, 32);
        if (g == 0)
            lP[(size_t)(b * KS + s) * N_ + qb + qs * 16 + l15] = l_acc;
    }
    unsigned short* accOut = accP + ((size_t)(b * KS + s) * C_) * N_;
#pragma unroll
    for (int ct = 0; ct < 2; ++ct)
#pragma unroll
        for (int qt = 0; qt < 4; ++qt)
#pragma unroll
            for (int r = 0; r < 4; ++r) {
                int c = wave * 32 + ct * 16 + 4 * g + r;
                accOut[(size_t)c * N_ + qb + qt * 16 + l15] = f2bf_hw(acc[ct][qt][r]);
            }
#undef STAGE
#undef KFLOAD
#undef VREAD
#undef PFREAD
#undef QKWR
#undef PVM
#undef BODY
}

// ---------------- combine splits (bf16 partials) + normalize + gamma*out + v ----------------
__global__ __launch_bounds__(256) void combine_k(
        const unsigned short* __restrict__ accP, const float* __restrict__ lP,
        const float* __restrict__ v_in, const float* __restrict__ gamma,
        float* __restrict__ out, int KS) {
    int i = blockIdx.x * 256 + threadIdx.x;
    const int nq4 = N_ / 4;
    int q0 = (i % nq4) * 4;
    int c  = (i / nq4) % C_;
    int b  = i / (nq4 * C_);
    float4_t num = {0.f, 0.f, 0.f, 0.f}, den = {0.f, 0.f, 0.f, 0.f};
    for (int s = 0; s < KS; ++s) {
        float4_t l4 = *(const float4_t*)(lP + (size_t)(b * KS + s) * N_ + q0);
        ushort4_t a4 = *(const ushort4_t*)(accP + ((size_t)(b * KS + s) * C_ + c) * N_ + q0);
#pragma unroll
        for (int j = 0; j < 4; ++j) {
            den[j] += l4[j];
            num[j] += bf2f(a4[j]);
        }
    }
    float gm = gamma[0];
    size_t idx = ((size_t)(b * C_ + c)) * N_ + q0;
    float4_t vi = *(const float4_t*)(v_in + idx);
    float4_t o;
#pragma unroll
    for (int j = 0; j < 4; ++j) o[j] = gm * num[j] / den[j] + vi[j];
    *(float4_t*)(out + idx) = o;
}

extern "C" void kernel_launch(void* const* d_in, const int* in_sizes, int n_in,
                              void* d_out, int out_size, void* d_ws, size_t ws_size,
                              hipStream_t stream) {
    (void)in_sizes; (void)n_in; (void)out_size;
    const float* v_in  = (const float*)d_in[0];
    const float* k_in  = (const float*)d_in[1];
    const float* q_in  = (const float*)d_in[2];
    const float* Wq    = (const float*)d_in[3];
    const float* bq    = (const float*)d_in[4];
    const float* Wk    = (const float*)d_in[5];
    const float* bk    = (const float*)d_in[6];
    const float* Wv    = (const float*)d_in[7];
    const float* bv    = (const float*)d_in[8];
    const float* gamma = (const float*)d_in[9];
    float* out = (float*)d_out;

    char* ws = (char*)d_ws;
    unsigned short* pvb = (unsigned short*)(ws + 0);          // 8.39 MB + 16 KB pad
    unsigned short* pqT = (unsigned short*)(ws + 8404992);    // 1 MB [b][n][32] (x log2e)
    unsigned short* pkT = (unsigned short*)(ws + 9453568);    // 1 MB + 24 KB pad (pipelined overread)
    unsigned short* Wqb = (unsigned short*)(ws + 10526720);   // 16 KB
    unsigned short* Wkb = (unsigned short*)(ws + 10543104);   // 16 KB
    unsigned short* Wvb = (unsigned short*)(ws + 10559488);   // 128 KB
    const size_t base2 = 10690560;

    // accP bf16: KS * 8.39 MB; lP f32: KS * 64 KB
    int KS = 2;
    while (KS > 1) {
        size_t need = base2 + (size_t)KS * 8388608 + (size_t)KS * 65536;
        if (need <= ws_size) break;
        KS >>= 1;
    }
    unsigned short* accP = (unsigned short*)(ws + base2);
    float* lP = (float*)(ws + base2 + (size_t)KS * 8388608);

    cast_w_k<<<320, 256, 0, stream>>>(Wq, Wk, Wv, Wqb, Wkb, Wvb);
    proj_qk_k<<<dim3(64, 4, 2), 256, 0, stream>>>(q_in, k_in, Wqb, Wkb, bq, bk, pqT, pkT);
    proj_v_k<<<dim3(256, 4), 256, 0, stream>>>(v_in, Wvb, bv, pvb);
    attn_split_k<<<dim3(64, KS, 4), 512, 0, stream>>>(pqT, pkT, pvb, accP, lP, KS);
    combine_k<<<4096, 256, 0, stream>>>(accP, lP, v_in, gamma, out, KS);
}

// Round 19
// 94.772 us; speedup vs baseline: 1.0512x; 1.0482x over previous
//
#include <hip/hip_runtime.h>
#include <hip/hip_bf16.h>

typedef __attribute__((ext_vector_type(8))) short short8_t;
typedef __attribute__((ext_vector_type(4))) unsigned short ushort4_t;
typedef __attribute__((ext_vector_type(4))) float float4_t;

#define B_   4
#define C_   256
#define N_   4096
#define DQK  32
#define LOG2E 1.4426950408889634f

#define VMCNT4   asm volatile("s_waitcnt vmcnt(4)" ::: "memory")
#define VMCNT0   asm volatile("s_waitcnt vmcnt(0)" ::: "memory")
#define LGKM0    asm volatile("s_waitcnt lgkmcnt(0)" ::: "memory")
#define SBAR     __builtin_amdgcn_s_barrier()
#define SCHEDB   __builtin_amdgcn_sched_barrier(0)

__device__ __forceinline__ unsigned short f2bf(float x) {
    union { float f; unsigned int u; } v; v.f = x;
    unsigned int r = v.u + 0x7FFFu + ((v.u >> 16) & 1u);   // RNE
    return (unsigned short)(r >> 16);
}
__device__ __forceinline__ unsigned short f2bf_hw(float x) {
    return __bfloat16_as_ushort(__float2bfloat16(x));      // hw RNE, pairs to cvt_pk
}
__device__ __forceinline__ float bf2f(unsigned short u) {
    union { unsigned int u; float f; } v; v.u = ((unsigned int)u) << 16; return v.f;
}

// ---------------- weight casts ----------------
__global__ __launch_bounds__(256) void cast_w_k(
        const float* __restrict__ Wq, const float* __restrict__ Wk,
        const float* __restrict__ Wv,
        unsigned short* __restrict__ Wqb, unsigned short* __restrict__ Wkb,
        unsigned short* __restrict__ Wvb) {
    int i = blockIdx.x * 256 + threadIdx.x;
    if (i < 8192)            Wqb[i] = f2bf(Wq[i]);
    else if (i < 16384)      Wkb[i - 8192] = f2bf(Wk[i - 8192]);
    else                     Wvb[i - 16384] = f2bf(Wv[i - 16384]);
}

// ---------------- pq / pk projection, reading x f32 [b][c][n] directly ----------------
__global__ __launch_bounds__(256) void proj_qk_k(
        const float* __restrict__ q_in, const float* __restrict__ k_in,
        const unsigned short* __restrict__ Wqb, const unsigned short* __restrict__ Wkb,
        const float* __restrict__ bq, const float* __restrict__ bk,
        unsigned short* __restrict__ pqT, unsigned short* __restrict__ pkT) {
    int b = blockIdx.y, z = blockIdx.z;
    const float* X = z ? k_in : q_in;
    const unsigned short* W = z ? Wkb : Wqb;
    const float* bias = z ? bk : bq;
    unsigned short* P = z ? pkT : pqT;
    float scl = z ? 1.0f : LOG2E;
    int tid = threadIdx.x, wave = tid >> 6, lane = tid & 63, l15 = lane & 15, g = lane >> 4;
    int nb = blockIdx.x * 64 + wave * 16;
    float4_t acc0 = {0.f, 0.f, 0.f, 0.f}, acc1 = {0.f, 0.f, 0.f, 0.f};
    const float* Xcol = X + (size_t)b * C_ * N_ + nb + l15;
#pragma unroll
    for (int kk = 0; kk < 8; ++kk) {
        short8_t a;
#pragma unroll
        for (int j = 0; j < 8; ++j)
            a[j] = (short)f2bf(Xcol[(size_t)(kk * 32 + 8 * g + j) * N_]);
        short8_t b0 = *(const short8_t*)(W + (size_t)l15 * C_ + kk * 32 + 8 * g);
        short8_t b1 = *(const short8_t*)(W + (size_t)(16 + l15) * C_ + kk * 32 + 8 * g);
        acc0 = __builtin_amdgcn_mfma_f32_16x16x32_bf16(a, b0, acc0, 0, 0, 0);
        acc1 = __builtin_amdgcn_mfma_f32_16x16x32_bf16(a, b1, acc1, 0, 0, 0);
    }
#pragma unroll
    for (int r = 0; r < 4; ++r) {
        int n = nb + 4 * g + r;
        P[((size_t)b * N_ + n) * DQK + l15]      = f2bf((acc0[r] + bias[l15]) * scl);
        P[((size_t)b * N_ + n) * DQK + 16 + l15] = f2bf((acc1[r] + bias[16 + l15]) * scl);
    }
}

// ---------------- pv projection: pv[b][c][m'] = Wv x v + bv, keys pi-permuted ----------------
__global__ __launch_bounds__(256) void proj_v_k(
        const float* __restrict__ v_in, const unsigned short* __restrict__ Wvb,
        const float* __restrict__ bv, unsigned short* __restrict__ pv) {
    int b = blockIdx.y;
    int tid = threadIdx.x, wave = tid >> 6, lane = tid & 63, l15 = lane & 15, g = lane >> 4;
    int mb = blockIdx.x * 16;
    int m = mb + l15;
    int k32 = m & 31;
    int pcol = (k32 < 16) ? ((k32 >> 2) * 8 + (k32 & 3))
                          : (((k32 - 16) >> 2) * 8 + 4 + (k32 & 3));
    int mcol = (m & ~31) + pcol;
    float4_t acc[4];
#pragma unroll
    for (int i = 0; i < 4; ++i) acc[i] = (float4_t){0.f, 0.f, 0.f, 0.f};
    const float* Vcol = v_in + (size_t)b * C_ * N_ + mb + l15;
#pragma unroll
    for (int kk = 0; kk < 8; ++kk) {
        short8_t bf;
#pragma unroll
        for (int j = 0; j < 8; ++j)
            bf[j] = (short)f2bf(Vcol[(size_t)(kk * 32 + 8 * g + j) * N_]);
#pragma unroll
        for (int ct = 0; ct < 4; ++ct) {
            short8_t af = *(const short8_t*)(Wvb + (size_t)(wave * 64 + ct * 16 + l15) * C_ + kk * 32 + 8 * g);
            acc[ct] = __builtin_amdgcn_mfma_f32_16x16x32_bf16(af, bf, acc[ct], 0, 0, 0);
        }
    }
#pragma unroll
    for (int ct = 0; ct < 4; ++ct)
#pragma unroll
        for (int r = 0; r < 4; ++r) {
            int c = wave * 64 + ct * 16 + 4 * g + r;
            pv[((size_t)b * C_ + c) * N_ + mcol] = f2bf(acc[ct][r] + bv[c]);
        }
}

// ---------------- flash attention: 8-wave blocks (r15, best-known) ----------------
// Wave w consumes PV for ch [32w,32w+32) x 64q (acc 2x4, 32 VGPR); waves 0-3
// also produce P for q-slice w. V single-buffer wave-private rows (LGKM0 drains
// own reads before re-stage). P 16KB ping-pong; ONE barrier/tile. KS=2 -> 512
// blocks = 2/CU, 16 waves/CU = 4 contexts/SIMD.
__global__ __launch_bounds__(512, 4) void attn_split_k(
        const unsigned short* __restrict__ pqT, const unsigned short* __restrict__ pkT,
        const unsigned short* __restrict__ pv,
        unsigned short* __restrict__ accP, float* __restrict__ lP, int KS) {
    __shared__ __align__(16) unsigned short VT[256][64];      // 32KB single buffer
    __shared__ __align__(16) short8_t Pl[2][4][2][4][16];     // 16KB [buf][qt][kh][g][l15]
    // XCD-chunked bijective swizzle (nwg % 8 == 0)
    int nqb = gridDim.x;
    int lin = blockIdx.x + nqb * (blockIdx.y + KS * blockIdx.z);
    int cpx = (nqb * KS * 4) >> 3;
    int sl  = (lin & 7) * cpx + (lin >> 3);
    int qbi = sl % nqb;
    int s   = (sl / nqb) % KS;
    int b   = sl / (nqb * KS);

    int kps = N_ / KS, ks0 = s * kps, nt = kps >> 6;
    int tid = threadIdx.x, wave = tid >> 6, lane = tid & 63, l15 = lane & 15, g = lane >> 4;
    int qb = qbi * 64;
    bool prod = wave < 4;
    int qs = wave & 3;
    int rl = lane >> 3, cl = (lane & 7) ^ rl;                 // staging source permute
    int sw = (l15 & 7) << 4;

    short8_t qf = *(const short8_t*)(pqT + ((size_t)b * N_ + qb + qs * 16 + l15) * DQK + 8 * g);
    float4_t acc[2][4];   // [ct][qt] -- 32 VGPR
#pragma unroll
    for (int i = 0; i < 2; ++i)
#pragma unroll
        for (int j = 0; j < 4; ++j) acc[i][j] = (float4_t){0.f, 0.f, 0.f, 0.f};
    float l_acc = 0.f;
    const float4_t zero4 = {0.f, 0.f, 0.f, 0.f};
    const char* pvb8 = (const char*)(pv + (size_t)b * C_ * N_);
    const char* pkTb = (const char*)pkT + (size_t)b * N_ * DQK * 2;

    // persistent byte offsets
    unsigned soff[4];
#pragma unroll
    for (int i = 0; i < 4; ++i)
        soff[i] = (unsigned)(((wave * 32 + i * 8 + rl) * N_ + ks0 + 8 * cl) * 2);
    unsigned koff = (unsigned)(((ks0 + l15) * DQK + 8 * g) * 2);
    // V read bases: rows wave*32 + ct*16 + l15 (imm ct*2048), XOR-swizzled chunks
    const char* vbA = (const char*)&VT[0][0] + (wave * 32 + l15) * 128 + ((16 * g) ^ sw);
    const char* vbB = (const char*)&VT[0][0] + (wave * 32 + l15) * 128 + ((64 + 16 * g) ^ sw);
    // P bases: byte = buf*8192 + qt*2048 + kh*1024 + g*256 + l15*16
    char* PlB = (char*)&Pl[0][0][0][0][0];
    const char* prd = PlB + g * 256 + l15 * 16;               // + buf + qt*2048 + kh*1024
    char* pwr = PlB + qs * 2048 + g * 256 + l15 * 16;         // + buf + kh*1024

    short8_t kf[4];

#define STAGE()                                                               \
    _Pragma("unroll")                                                         \
    for (int i_ = 0; i_ < 4; ++i_) {                                          \
        __builtin_amdgcn_global_load_lds(                                     \
            (const __attribute__((address_space(1))) unsigned int*)(const void*)(pvb8 + soff[i_]), \
            (__attribute__((address_space(3))) unsigned int*)(void*)((char*)&VT[0][0] + (wave * 32 + i_ * 8) * 128), \
            16, 0, 0);                                                        \
        soff[i_] += 128;                                                      \
    }

#define KFLOAD()                                                              \
    _Pragma("unroll")                                                         \
    for (int it_ = 0; it_ < 4; ++it_)                                         \
        kf[it_] = *(const short8_t*)(pkTb + koff + it_ * 1024);               \
    koff += 4096;

#define VREAD(DST)                                                            \
    _Pragma("unroll")                                                         \
    for (int ct_ = 0; ct_ < 2; ++ct_) {                                       \
        DST[ct_][0] = *(const short8_t*)(vbA + ct_ * 2048);                   \
        DST[ct_][1] = *(const short8_t*)(vbB + ct_ * 2048);                   \
    }

#define PFREAD(DST, CBOFF)                                                    \
    _Pragma("unroll")                                                         \
    for (int qt_ = 0; qt_ < 4; ++qt_)                                         \
        _Pragma("unroll")                                                     \
        for (int kh_ = 0; kh_ < 2; ++kh_)                                     \
            DST[qt_][kh_] = *(const short8_t*)(prd + (CBOFF) + qt_ * 2048 + kh_ * 1024);

// QK -> exp2 -> l_acc -> pack -> 2x ds_write_b128 to Pl[NB]
#define QKWR(NBOFF)                                                           \
    {                                                                          \
        float4_t sv_[4];                                                       \
        _Pragma("unroll")                                                      \
        for (int it_ = 0; it_ < 4; ++it_)                                      \
            sv_[it_] = __builtin_amdgcn_mfma_f32_16x16x32_bf16(kf[it_], qf, zero4, 0, 0, 0); \
        float p_[16];                                                          \
        _Pragma("unroll")                                                      \
        for (int it_ = 0; it_ < 4; ++it_)                                      \
            _Pragma("unroll")                                                  \
            for (int r_ = 0; r_ < 4; ++r_)                                     \
                p_[it_ * 4 + r_] = exp2f(sv_[it_][r_]);                        \
        l_acc += ((p_[0] + p_[1]) + (p_[2] + p_[3])) + ((p_[4] + p_[5]) + (p_[6] + p_[7])) \
               + ((p_[8] + p_[9]) + (p_[10] + p_[11])) + ((p_[12] + p_[13]) + (p_[14] + p_[15])); \
        short8_t pb0_, pb1_;                                                   \
        _Pragma("unroll")                                                      \
        for (int j_ = 0; j_ < 4; ++j_) {                                       \
            pb0_[j_]     = (short)f2bf_hw(p_[j_]);                             \
            pb0_[4 + j_] = (short)f2bf_hw(p_[4 + j_]);                         \
            pb1_[j_]     = (short)f2bf_hw(p_[8 + j_]);                         \
            pb1_[4 + j_] = (short)f2bf_hw(p_[12 + j_]);                        \
        }                                                                      \
        *(short8_t*)(pwr + (NBOFF))        = pb0_;                             \
        *(short8_t*)(pwr + (NBOFF) + 1024) = pb1_;                             \
    }

#define PVM(VF, PF)                                                           \
    _Pragma("unroll")                                                         \
    for (int ct_ = 0; ct_ < 2; ++ct_)                                         \
        _Pragma("unroll")                                                     \
        for (int qt_ = 0; qt_ < 4; ++qt_) {                                   \
            acc[ct_][qt_] = __builtin_amdgcn_mfma_f32_16x16x32_bf16(VF[ct_][0], PF[qt_][0], acc[ct_][qt_], 0, 0, 0); \
            acc[ct_][qt_] = __builtin_amdgcn_mfma_f32_16x16x32_bf16(VF[ct_][1], PF[qt_][1], acc[ct_][qt_], 0, 0, 0); \
        }

// body(T): drain own STAGE(T); read V(T)+P(T); drain; re-stage V(T+1);
// producers: QKWR P(T+1) + prefetch kf; PV(T); barrier.
#define BODY(T, CBOFF, NBOFF)                                                 \
    {                                                                          \
        if (prod) { VMCNT4; } else { VMCNT0; }                                 \
        SCHEDB;                                                                \
        short8_t vf_[2][2], pf_[4][2];                                         \
        VREAD(vf_)                                                             \
        PFREAD(pf_, CBOFF)                                                     \
        LGKM0; SCHEDB;                                                         \
        if ((T) + 1 < nt) {                                                    \
            STAGE()                                                            \
            SCHEDB;                                                            \
            if (prod) { QKWR(NBOFF) KFLOAD() }                                 \
            SCHEDB;                                                            \
        }                                                                      \
        __builtin_amdgcn_s_setprio(1);                                         \
        PVM(vf_, pf_)                                                          \
        __builtin_amdgcn_s_setprio(0);                                         \
        LGKM0; SCHEDB;                                                         \
        SBAR;                                                                  \
    }

    // ---- prologue: stage V(0); producers: kf(0) -> P(0) -> kf(1) ----
    STAGE()
    if (prod) {
        KFLOAD()
        QKWR(0)          // P(0) -> buf0 (compiler waits kf; also drains STAGE)
        KFLOAD()
    }
    LGKM0; SCHEDB;
    SBAR;

    for (int t = 0; t < nt; t += 2) {
        BODY(t,     0, 8192)     // read buf0, write buf1
        BODY(t + 1, 8192, 0)     // read buf1, write buf0
    }

    // ---- epilogue: l (producers) + bf16 partial acc ----
    if (prod) {
        l_acc += __shfl_xor(l_acc, 16);
        l_acc += __shfl_xor(l_acc, 32);
        if (g == 0)
            lP[(size_t)(b * KS + s) * N_ + qb + qs * 16 + l15] = l_acc;
    }
    unsigned short* accOut = accP + ((size_t)(b * KS + s) * C_) * N_;
#pragma unroll
    for (int ct = 0; ct < 2; ++ct)
#pragma unroll
        for (int qt = 0; qt < 4; ++qt)
#pragma unroll
            for (int r = 0; r < 4; ++r) {
                int c = wave * 32 + ct * 16 + 4 * g + r;
                accOut[(size_t)c * N_ + qb + qt * 16 + l15] = f2bf_hw(acc[ct][qt][r]);
            }
#undef STAGE
#undef KFLOAD
#undef VREAD
#undef PFREAD
#undef QKWR
#undef PVM
#undef BODY
}

// ---------------- combine splits (bf16 partials) + normalize + gamma*out + v ----------------
__global__ __launch_bounds__(256) void combine_k(
        const unsigned short* __restrict__ accP, const float* __restrict__ lP,
        const float* __restrict__ v_in, const float* __restrict__ gamma,
        float* __restrict__ out, int KS) {
    int i = blockIdx.x * 256 + threadIdx.x;
    const int nq4 = N_ / 4;
    int q0 = (i % nq4) * 4;
    int c  = (i / nq4) % C_;
    int b  = i / (nq4 * C_);
    float4_t num = {0.f, 0.f, 0.f, 0.f}, den = {0.f, 0.f, 0.f, 0.f};
    for (int s = 0; s < KS; ++s) {
        float4_t l4 = *(const float4_t*)(lP + (size_t)(b * KS + s) * N_ + q0);
        ushort4_t a4 = *(const ushort4_t*)(accP + ((size_t)(b * KS + s) * C_ + c) * N_ + q0);
#pragma unroll
        for (int j = 0; j < 4; ++j) {
            den[j] += l4[j];
            num[j] += bf2f(a4[j]);
        }
    }
    float gm = gamma[0];
    size_t idx = ((size_t)(b * C_ + c)) * N_ + q0;
    float4_t vi = *(const float4_t*)(v_in + idx);
    float4_t o;
#pragma unroll
    for (int j = 0; j < 4; ++j) o[j] = gm * num[j] / den[j] + vi[j];
    *(float4_t*)(out + idx) = o;
}

extern "C" void kernel_launch(void* const* d_in, const int* in_sizes, int n_in,
                              void* d_out, int out_size, void* d_ws, size_t ws_size,
                              hipStream_t stream) {
    (void)in_sizes; (void)n_in; (void)out_size;
    const float* v_in  = (const float*)d_in[0];
    const float* k_in  = (const float*)d_in[1];
    const float* q_in  = (const float*)d_in[2];
    const float* Wq    = (const float*)d_in[3];
    const float* bq    = (const float*)d_in[4];
    const float* Wk    = (const float*)d_in[5];
    const float* bk    = (const float*)d_in[6];
    const float* Wv    = (const float*)d_in[7];
    const float* bv    = (const float*)d_in[8];
    const float* gamma = (const float*)d_in[9];
    float* out = (float*)d_out;

    char* ws = (char*)d_ws;
    unsigned short* pvb = (unsigned short*)(ws + 0);          // 8.39 MB + 16 KB pad
    unsigned short* pqT = (unsigned short*)(ws + 8404992);    // 1 MB [b][n][32] (x log2e)
    unsigned short* pkT = (unsigned short*)(ws + 9453568);    // 1 MB + 24 KB pad (pipelined overread)
    unsigned short* Wqb = (unsigned short*)(ws + 10526720);   // 16 KB
    unsigned short* Wkb = (unsigned short*)(ws + 10543104);   // 16 KB
    unsigned short* Wvb = (unsigned short*)(ws + 10559488);   // 128 KB
    const size_t base2 = 10690560;

    // accP bf16: KS * 8.39 MB; lP f32: KS * 64 KB
    int KS = 2;
    while (KS > 1) {
        size_t need = base2 + (size_t)KS * 8388608 + (size_t)KS * 65536;
        if (need <= ws_size) break;
        KS >>= 1;
    }
    unsigned short* accP = (unsigned short*)(ws + base2);
    float* lP = (float*)(ws + base2 + (size_t)KS * 8388608);

    cast_w_k<<<320, 256, 0, stream>>>(Wq, Wk, Wv, Wqb, Wkb, Wvb);
    proj_qk_k<<<dim3(64, 4, 2), 256, 0, stream>>>(q_in, k_in, Wqb, Wkb, bq, bk, pqT, pkT);
    proj_v_k<<<dim3(256, 4), 256, 0, stream>>>(v_in, Wvb, bv, pvb);
    attn_split_k<<<dim3(64, KS, 4), 512, 0, stream>>>(pqT, pkT, pvb, accP, lP, KS);
    combine_k<<<4096, 256, 0, stream>>>(accP, lP, v_in, gamma, out, KS);
}